// Round 1
// baseline (10004.021 us; speedup 1.0000x reference)
//
#include <hip/hip_runtime.h>
#include <hip/hip_bf16.h>
#include <math.h>

#define NB 8
#define NS 512
#define NE 384
#define NH 7
#define ND 54
#define NL 7
#define NV 32000
#define NFF 2304
#define NHD 378       // H*D
#define NQKV 1134     // 3*H*D
#define NM 4096       // B*S

__device__ inline float wave_sum(float v) {
#pragma unroll
    for (int o = 32; o > 0; o >>= 1) v += __shfl_xor(v, o);
    return v;
}
__device__ inline float wave_max(float v) {
#pragma unroll
    for (int o = 32; o > 0; o >>= 1) v = fmaxf(v, __shfl_xor(v, o));
    return v;
}

// ---------------- embedding ----------------
__global__ __launch_bounds__(256) void embed_kernel(
    const int* __restrict__ ids, const float* __restrict__ tok,
    const float* __restrict__ pos, float* __restrict__ x)
{
    int i = blockIdx.x * 256 + threadIdx.x;   // < NM*NE
    if (i >= NM * NE) return;
    int e  = i % NE;
    int bs = i / NE;
    int s  = bs % NS;
    x[i] = tok[(size_t)ids[bs] * NE + e] + pos[s * NE + e];
}

// ---------------- layernorm (1 wave per row) ----------------
__global__ __launch_bounds__(64) void ln_kernel(
    const float* __restrict__ x, const float* __restrict__ g,
    const float* __restrict__ b, float* __restrict__ y)
{
    int row = blockIdx.x;
    const float* xr = x + (size_t)row * NE;
    float* yr = y + (size_t)row * NE;
    int t = threadIdx.x;
    float v[6];
    float s = 0.f;
#pragma unroll
    for (int i = 0; i < 6; ++i) { v[i] = xr[t + i * 64]; s += v[i]; }
    s = wave_sum(s);
    float mean = s * (1.f / NE);
    float s2 = 0.f;
#pragma unroll
    for (int i = 0; i < 6; ++i) { float d = v[i] - mean; s2 += d * d; }
    s2 = wave_sum(s2);
    float inv = rsqrtf(s2 * (1.f / NE) + 1e-5f);
#pragma unroll
    for (int i = 0; i < 6; ++i) {
        int e = t + i * 64;
        yr[e] = (v[i] - mean) * inv * g[e] + b[e];
    }
}

// ---------------- generic tiled fp32 GEMM ----------------
// C[M,N] = epi(A[M,K] @ B[K,N] + bias[N])
// EPI: 0 = store, 1 = C += (residual in-place), 2 = GELU(exact)
template<int EPI>
__global__ __launch_bounds__(256) void gemm_f32(
    const float* __restrict__ A, const float* __restrict__ B,
    const float* __restrict__ bias, float* __restrict__ C,
    int M, int N, int K)
{
    __shared__ float As[16][68];
    __shared__ float Bs[16][68];
    int tid = threadIdx.x;
    int bm = blockIdx.y * 64;
    int bn = blockIdx.x * 64;
    int ty = tid >> 4;   // 0..15
    int tx = tid & 15;   // 0..15
    float acc[4][4] = {};
    for (int k0 = 0; k0 < K; k0 += 16) {
#pragma unroll
        for (int i = 0; i < 4; ++i) {
            int lin = tid + i * 256;
            int r = lin >> 4;     // m  0..63
            int c = lin & 15;     // k  0..15
            float val = 0.f;
            if (k0 + c < K) val = A[(size_t)(bm + r) * K + k0 + c];
            As[c][r] = val;
        }
#pragma unroll
        for (int i = 0; i < 4; ++i) {
            int lin = tid + i * 256;
            int r = lin >> 6;     // k 0..15
            int c = lin & 63;     // n 0..63
            float val = 0.f;
            if ((k0 + r < K) && (bn + c < N)) val = B[(size_t)(k0 + r) * N + bn + c];
            Bs[r][c] = val;
        }
        __syncthreads();
#pragma unroll
        for (int kk = 0; kk < 16; ++kk) {
            float4 a4 = *reinterpret_cast<const float4*>(&As[kk][ty * 4]);
            float4 b4 = *reinterpret_cast<const float4*>(&Bs[kk][tx * 4]);
            float av[4] = {a4.x, a4.y, a4.z, a4.w};
            float bv[4] = {b4.x, b4.y, b4.z, b4.w};
#pragma unroll
            for (int i = 0; i < 4; ++i)
#pragma unroll
                for (int j = 0; j < 4; ++j)
                    acc[i][j] += av[i] * bv[j];
        }
        __syncthreads();
    }
#pragma unroll
    for (int i = 0; i < 4; ++i) {
        int m = bm + ty * 4 + i;
#pragma unroll
        for (int j = 0; j < 4; ++j) {
            int n = bn + tx * 4 + j;
            if (n < N) {
                float v = acc[i][j] + bias[n];
                size_t idx = (size_t)m * N + n;
                if (EPI == 1) v += C[idx];
                if (EPI == 2) v = 0.5f * v * (1.f + erff(v * 0.70710678118654752f));
                C[idx] = v;
            }
        }
    }
}

// ---------------- QKV weight/bias repack ----------------
// wsW[l][e][n] with n = t*378 + h*54 + d  <-  W{q,k,v}[l,h,e,d]
__global__ __launch_bounds__(256) void repack_w(
    const float* __restrict__ Wq, const float* __restrict__ Wk,
    const float* __restrict__ Wv, float* __restrict__ wsW)
{
    int i = blockIdx.x * 256 + threadIdx.x;
    if (i >= NL * NE * NQKV) return;
    int l = i / (NE * NQKV);
    int rem = i % (NE * NQKV);
    int e = rem / NQKV;
    int n = rem % NQKV;
    int t = n / NHD;
    int r = n % NHD;
    int h = r / ND;
    int d = r % ND;
    const float* W = (t == 0) ? Wq : (t == 1) ? Wk : Wv;
    wsW[i] = W[((size_t)(l * NH + h) * NE + e) * ND + d];
}

__global__ __launch_bounds__(256) void repack_b(
    const float* __restrict__ bq, const float* __restrict__ bk,
    const float* __restrict__ bv, float* __restrict__ wsB)
{
    int i = blockIdx.x * 256 + threadIdx.x;
    if (i >= NL * NQKV) return;
    int l = i / NQKV;
    int n = i % NQKV;
    int t = n / NHD;
    int r = n % NHD;
    int h = r / ND;
    int d = r % ND;
    const float* bb = (t == 0) ? bq : (t == 1) ? bk : bv;
    wsB[i] = bb[(l * NH + h) * ND + d];
}

// ---------------- attention: 1 wave per (b,h,q-row) ----------------
__global__ __launch_bounds__(64) void attn_kernel(
    const float* __restrict__ qkv, float* __restrict__ o)
{
    int qi = blockIdx.x;
    int h  = blockIdx.y;
    int b  = blockIdx.z;
    int lane = threadIdx.x;

    __shared__ float qs[56];
    __shared__ float sc[NS];

    const float* qrow = qkv + (size_t)(b * NS + qi) * NQKV + h * ND;
    if (lane < ND) qs[lane] = qrow[lane];
    __syncthreads();

    const float scale = 0.13608276348795434f;  // 54^-0.5
    float mx = -1e30f;
    for (int j = lane; j <= qi; j += 64) {
        const float* krow = qkv + (size_t)(b * NS + j) * NQKV + NHD + h * ND;
        float s = 0.f;
#pragma unroll
        for (int d = 0; d < ND; ++d) s += qs[d] * krow[d];
        s *= scale;
        sc[j] = s;
        mx = fmaxf(mx, s);
    }
    mx = wave_max(mx);
    float sum = 0.f;
    for (int j = lane; j <= qi; j += 64) {
        float p = __expf(sc[j] - mx);
        sc[j] = p;
        sum += p;
    }
    sum = wave_sum(sum);
    float inv = 1.f / sum;
    __syncthreads();

    if (lane < ND) {
        float acc = 0.f;
        const float* vbase = qkv + (size_t)b * NS * NQKV + 2 * NHD + h * ND + lane;
        for (int j = 0; j <= qi; ++j)
            acc += sc[j] * vbase[(size_t)j * NQKV];
        o[(size_t)(b * NS + qi) * NHD + h * ND + lane] = acc * inv;
    }
}

// ---------------- loss ----------------
__global__ void zero_kernel(float* p) { p[0] = 0.f; }

__global__ __launch_bounds__(256) void loss_kernel(
    const float* __restrict__ logits, const int* __restrict__ tgt,
    float* __restrict__ acc)
{
    __shared__ float red[4];
    int row = blockIdx.x;
    const float* lr = logits + (size_t)row * NV;
    int tid = threadIdx.x;

    float mx = -1e30f;
    for (int j = tid; j < NV; j += 256) mx = fmaxf(mx, lr[j]);
    mx = wave_max(mx);
    if ((tid & 63) == 0) red[tid >> 6] = mx;
    __syncthreads();
    mx = fmaxf(fmaxf(red[0], red[1]), fmaxf(red[2], red[3]));
    __syncthreads();

    float sum = 0.f;
    for (int j = tid; j < NV; j += 256) sum += expf(lr[j] - mx);
    sum = wave_sum(sum);
    if ((tid & 63) == 0) red[tid >> 6] = sum;
    __syncthreads();
    sum = red[0] + red[1] + red[2] + red[3];

    if (tid == 0) {
        float lp = lr[tgt[row]] - mx - logf(sum);
        atomicAdd(acc, -lp);
    }
}

__global__ void finalize_loss(const float* __restrict__ acc, float* __restrict__ out)
{
    out[0] = acc[0] * (1.f / NM);
}

// ---------------- launch ----------------
extern "C" void kernel_launch(void* const* d_in, const int* in_sizes, int n_in,
                              void* d_out, int out_size, void* d_ws, size_t ws_size,
                              hipStream_t stream)
{
    const int*   ids  = (const int*)d_in[0];
    const int*   tgt  = (const int*)d_in[1];
    const float* tok  = (const float*)d_in[2];
    const float* pos  = (const float*)d_in[3];
    const float* Wq   = (const float*)d_in[4];
    const float* bq   = (const float*)d_in[5];
    const float* Wk   = (const float*)d_in[6];
    const float* bk   = (const float*)d_in[7];
    const float* Wv   = (const float*)d_in[8];
    const float* bv   = (const float*)d_in[9];
    const float* Wc   = (const float*)d_in[10];
    const float* bc   = (const float*)d_in[11];
    const float* g1   = (const float*)d_in[12];
    const float* b1   = (const float*)d_in[13];
    const float* g2   = (const float*)d_in[14];
    const float* b2   = (const float*)d_in[15];
    const float* W1   = (const float*)d_in[16];
    const float* bf1  = (const float*)d_in[17];
    const float* W2   = (const float*)d_in[18];
    const float* bf2  = (const float*)d_in[19];
    const float* gf   = (const float*)d_in[20];
    const float* bfin = (const float*)d_in[21];
    const float* Wout = (const float*)d_in[22];
    const float* bout = (const float*)d_in[23];

    float* out = (float*)d_out;
    float* ws  = (float*)d_ws;

    // workspace layout (floats)
    float* x      = ws;                       // NM*NE       = 1572864
    float* xn     = x      + (size_t)NM * NE; // 1572864
    float* qkvbuf = xn     + (size_t)NM * NE; // NM*NQKV     = 4644864
    float* obuf   = qkvbuf + (size_t)NM * NQKV; // NM*NHD    = 1548288
    float* hbuf   = obuf   + (size_t)NM * NHD;  // NM*NFF    = 9437184
    float* qkvW   = hbuf   + (size_t)NM * NFF;  // NL*NE*NQKV= 3048192
    float* qkvB   = qkvW   + (size_t)NL * NE * NQKV; // NL*NQKV = 7938
    float* acc    = qkvB   + (size_t)NL * NQKV;      // 1

    // repack QKV weights once per call
    repack_w<<<(NL * NE * NQKV + 255) / 256, 256, 0, stream>>>(Wq, Wk, Wv, qkvW);
    repack_b<<<(NL * NQKV + 255) / 256, 256, 0, stream>>>(bq, bk, bv, qkvB);

    embed_kernel<<<(NM * NE + 255) / 256, 256, 0, stream>>>(ids, tok, pos, x);

    for (int l = 0; l < NL; ++l) {
        ln_kernel<<<NM, 64, 0, stream>>>(x, g1 + l * NE, b1 + l * NE, xn);
        gemm_f32<0><<<dim3((NQKV + 63) / 64, NM / 64), 256, 0, stream>>>(
            xn, qkvW + (size_t)l * NE * NQKV, qkvB + l * NQKV, qkvbuf, NM, NQKV, NE);
        attn_kernel<<<dim3(NS, NH, NB), 64, 0, stream>>>(qkvbuf, obuf);
        gemm_f32<1><<<dim3(NE / 64, NM / 64), 256, 0, stream>>>(
            obuf, Wc + (size_t)l * NHD * NE, bc + l * NE, x, NM, NE, NHD);
        ln_kernel<<<NM, 64, 0, stream>>>(x, g2 + l * NE, b2 + l * NE, xn);
        gemm_f32<2><<<dim3(NFF / 64, NM / 64), 256, 0, stream>>>(
            xn, W1 + (size_t)l * NE * NFF, bf1 + l * NFF, hbuf, NM, NFF, NE);
        gemm_f32<1><<<dim3(NE / 64, NM / 64), 256, 0, stream>>>(
            hbuf, W2 + (size_t)l * NFF * NE, bf2 + l * NE, x, NM, NE, NFF);
    }

    ln_kernel<<<NM, 64, 0, stream>>>(x, gf, bfin, xn);
    gemm_f32<0><<<dim3(NV / 64, NM / 64), 256, 0, stream>>>(
        xn, Wout, bout, out, NM, NV, NE);

    zero_kernel<<<1, 1, 0, stream>>>(acc);
    loss_kernel<<<NM, 256, 0, stream>>>(out, tgt, acc);
    finalize_loss<<<1, 1, 0, stream>>>(acc, out + (size_t)NM * NV);
}